// Round 8
// baseline (162.397 us; speedup 1.0000x reference)
//
#include <hip/hip_runtime.h>
#include <hip/hip_bf16.h>

// RestrictedNN DAG. Round 8: fold gene affine into W0 (W0g = Wg*W0, bias0),
// TB=4 for max co-residency (LDS 17.5KB), lazy W1t/W2t fragment loads.
// B=4096, L0=512 leaves (G=8,H=16), L1=64, L2=8 (FAN=8), root 128->16.
// h0 = sigmoid(x @ W0g + bias0) exactly == sigmoid((x*Wg+bg) @ W0).

#define TB 4
#define H0S 1032     // ushorts per h0 row (1024+8): 516 dw == 4 mod 32
#define H1S 136      // ushorts per h1 row (128+8)

typedef __attribute__((ext_vector_type(8))) short short8;
typedef __attribute__((ext_vector_type(4))) float floatx4;
typedef __attribute__((address_space(3))) void lds_void;
typedef const __attribute__((address_space(1))) void gbl_void;

__device__ __forceinline__ float sigf(float v) {
    return __builtin_amdgcn_rcpf(1.0f + __expf(-v));
}
__device__ __forceinline__ unsigned int f2bf_u32(float f) {   // RNE, bf16 in low 16
    unsigned int u = __builtin_bit_cast(unsigned int, f);
    return (u + 0x7fffu + ((u >> 16) & 1u)) >> 16;
}
__device__ __forceinline__ unsigned short f2bf(float f) {
    return (unsigned short)f2bf_u32(f);
}
__device__ __forceinline__ unsigned int f2bf2(float lo, float hi) {
    return f2bf_u32(lo) | (f2bf_u32(hi) << 16);
}

// ---- prep: W1/W2 -> bf16 fragment layout; W0g = Wg*W0, bias0 = bg@W0 ----
__global__ __launch_bounds__(256) void k_prep(
    const float* __restrict__ W1, const float* __restrict__ W2,
    const float* __restrict__ W0, const float* __restrict__ Wg,
    const float* __restrict__ bg,
    unsigned short* __restrict__ W1t, unsigned short* __restrict__ W2t,
    float* __restrict__ W0g, float* __restrict__ bias0)
{
    __shared__ float wl[128 * 17];
    const int mb = blockIdx.x;
    const int tid = threadIdx.x;
    if (mb < 72) {                          // 0..63 -> W1t, 64..71 -> W2t
        const float* src = (mb < 64) ? (W1 + (size_t)mb * 2048)
                                     : (W2 + (size_t)(mb - 64) * 2048);
        unsigned short* dst = (mb < 64) ? (W1t + (size_t)mb * 2048)
                                        : (W2t + (size_t)(mb - 64) * 2048);
#pragma unroll
        for (int i = 0; i < 8; ++i) {
            const int idx = tid + i * 256;  // [k][h] in, coalesced
            wl[(idx >> 4) * 17 + (idx & 15)] = src[idx];
        }
        __syncthreads();
#pragma unroll
        for (int i = 0; i < 4; ++i) {
            const int u = tid + i * 256;    // uint index over [h][k] bf16 out
            const int h = u >> 6;
            const int k = (u & 63) * 2;
            ((unsigned int*)dst)[u] = f2bf2(wl[k * 17 + h], wl[(k + 1) * 17 + h]);
        }
    } else {                                // 72..103: W0g + bias0, 16 modules/block
        const int m = (mb - 72) * 16 + (tid >> 4);
        const int h = tid & 15;
        float bias = 0.f;
#pragma unroll
        for (int g = 0; g < 8; ++g) {
            const float w0 = W0[(size_t)m * 128 + g * 16 + h];
            W0g[((size_t)m * 16 + h) * 8 + g] = Wg[m * 8 + g] * w0;
            bias = fmaf(bg[m * 8 + g], w0, bias);
        }
        bias0[m * 16 + h] = bias;
    }
}

__global__ __launch_bounds__(256) void k_tree(
    const float* __restrict__ x, const float* __restrict__ W0g,
    const float* __restrict__ bias0,
    const unsigned short* __restrict__ W1t, const unsigned short* __restrict__ W2t,
    float* __restrict__ h2ws)
{
    __shared__ __align__(16) float xs[TB * 512];             // 8192 B, DMA layout (no pad)
    __shared__ __align__(16) unsigned short h0s[TB * H0S];   // 8256 B
    __shared__ __align__(16) unsigned short h1s[TB * H1S];   // 1088 B  (17.5 KB)

    const int tid  = threadIdx.x;
    const int s    = blockIdx.x & 7;          // subtree == h2 module (== XCD slice)
    const int b0   = (blockIdx.x >> 3) * TB;  // batch tile base
    const int lane = tid & 63;
    const int wv   = tid >> 6;

    // ---------- async DMA: x tile (4 rows x 2KB) -> LDS, 2 issues/wave ----------
    {
        const float* xbase = x + (size_t)b0 * 4096 + s * 512;
#pragma unroll
        for (int t = 0; t < 2; ++t) {
            const int i    = (t * 4 + wv) * 64 + lane;   // float4 units over 4x128
            const int row  = i >> 7;
            const int colf = (i & 127) * 4;
            gbl_void* gp = (gbl_void*)(xbase + (size_t)row * 4096 + colf);
            lds_void* lp = (lds_void*)((char*)xs + (size_t)(t * 4 + wv) * 1024);
            __builtin_amdgcn_global_load_lds(gp, lp, 16, 0, 0);
        }
    }

    // ---------- weight prefetch under the DMA shadow ----------
    const int m_l = tid >> 2;                 // local leaf module 0..63
    const int hq  = tid & 3;                  // h quad
    const int m   = s * 64 + m_l;
    float4 wA[4][2];                          // [hi][half]: W0g[m][hq*4+hi][g]
#pragma unroll
    for (int hi = 0; hi < 4; ++hi) {
        wA[hi][0] = *(const float4*)(W0g + ((size_t)m * 16 + hq * 4 + hi) * 8);
        wA[hi][1] = *(const float4*)(W0g + ((size_t)m * 16 + hq * 4 + hi) * 8 + 4);
    }
    const float4 bv = *(const float4*)(bias0 + m * 16 + hq * 4);
    const float bb[4] = {bv.x, bv.y, bv.z, bv.w};

    const int n = lane & 15, q = lane >> 4;
    short8 w1r0[4];                           // phase-B module j0 = wv*2 fragments
    {
        const unsigned short* w1m = W1t + ((size_t)(s * 8 + wv * 2) * 16 + n) * 128 + q * 8;
#pragma unroll
        for (int ks = 0; ks < 4; ++ks) w1r0[ks] = *(const short8*)(w1m + ks * 32);
    }
    __syncthreads();   // drains DMA + weight loads, orders LDS

    // ---------- phase A: h0 = sigmoid(x @ W0g + bias0) ----------
    {
        const float* xb = &xs[m_l * 8];
        unsigned short* h0base = &h0s[m_l * 16 + hq * 4];
#pragma unroll
        for (int b = 0; b < TB; ++b) {
            const float4 x0 = *(const float4*)(xb + b * 512);
            const float4 x1 = *(const float4*)(xb + b * 512 + 4);
            float a[4];
#pragma unroll
            for (int hi = 0; hi < 4; ++hi) {
                float v = bb[hi];
                v = fmaf(x0.x, wA[hi][0].x, v);
                v = fmaf(x0.y, wA[hi][0].y, v);
                v = fmaf(x0.z, wA[hi][0].z, v);
                v = fmaf(x0.w, wA[hi][0].w, v);
                v = fmaf(x1.x, wA[hi][1].x, v);
                v = fmaf(x1.y, wA[hi][1].y, v);
                v = fmaf(x1.z, wA[hi][1].z, v);
                v = fmaf(x1.w, wA[hi][1].w, v);
                a[hi] = v;
            }
            *(uint2*)(h0base + b * H0S) =
                make_uint2(f2bf2(sigf(a[0]), sigf(a[1])), f2bf2(sigf(a[2]), sigf(a[3])));
        }
    }
    __syncthreads();

    // ---------- phase B: h1 MFMA, wave wv -> modules {2wv, 2wv+1} ----------
    // TB=4 < M=16: A rows duplicate (n&3); C rows >=4 discarded (q==0 writes).
    {
        const int j0 = wv * 2;
        short8 w1r1[4];                        // lazy: module j0+1 (hidden by j0 work)
        const unsigned short* w1m1 = W1t + ((size_t)(s * 8 + j0 + 1) * 16 + n) * 128 + q * 8;
#pragma unroll
        for (int ks = 0; ks < 4; ++ks) w1r1[ks] = *(const short8*)(w1m1 + ks * 32);

        const unsigned short* am0 = &h0s[(n & 3) * H0S + j0 * 128 + q * 8];
        floatx4 acc0 = {0.f, 0.f, 0.f, 0.f};
#pragma unroll
        for (int ks = 0; ks < 4; ++ks) {
            const short8 av = *(const short8*)(am0 + ks * 32);
            acc0 = __builtin_amdgcn_mfma_f32_16x16x32_bf16(av, w1r0[ks], acc0, 0, 0, 0);
        }
        if (q == 0) {
#pragma unroll
            for (int r = 0; r < 4; ++r)
                h1s[r * H1S + j0 * 16 + n] = f2bf(sigf(acc0[r]));
        }
        const unsigned short* am1 = am0 + 128;
        floatx4 acc1 = {0.f, 0.f, 0.f, 0.f};
#pragma unroll
        for (int ks = 0; ks < 4; ++ks) {
            const short8 av = *(const short8*)(am1 + ks * 32);
            acc1 = __builtin_amdgcn_mfma_f32_16x16x32_bf16(av, w1r1[ks], acc1, 0, 0, 0);
        }
        if (q == 0) {
#pragma unroll
            for (int r = 0; r < 4; ++r)
                h1s[r * H1S + (j0 + 1) * 16 + n] = f2bf(sigf(acc1[r]));
        }
    }
    __syncthreads();

    // ---------- phase C: h2 MFMA (module s), wave 0 only ----------
    if (wv == 0) {
        short8 w2r[4];
        const unsigned short* w2m = W2t + ((size_t)s * 16 + n) * 128 + q * 8;
#pragma unroll
        for (int ks = 0; ks < 4; ++ks) w2r[ks] = *(const short8*)(w2m + ks * 32);
        const unsigned short* am = &h1s[(n & 3) * H1S + q * 8];
        floatx4 acc = {0.f, 0.f, 0.f, 0.f};
#pragma unroll
        for (int ks = 0; ks < 4; ++ks) {
            const short8 av = *(const short8*)(am + ks * 32);
            acc = __builtin_amdgcn_mfma_f32_16x16x32_bf16(av, w2r[ks], acc, 0, 0, 0);
        }
        if (q == 0) {
#pragma unroll
            for (int r = 0; r < 4; ++r)
                h2ws[(size_t)(b0 + r) * 128 + s * 16 + n] = sigf(acc[r]);
        }
    }
}

// ---------- kernel: root (128->16, sigmoid) + final dot(16) ----------
__global__ __launch_bounds__(128) void k_root(
    const float* __restrict__ h2ws, const float* __restrict__ W3,
    const float* __restrict__ Wf, float* __restrict__ out)
{
    __shared__ float w3s[2048];
    __shared__ float wfs[16];
    const int tid = threadIdx.x;
#pragma unroll
    for (int t = 0; t < 16; ++t) w3s[tid + t * 128] = W3[tid + t * 128];
    if (tid < 16) wfs[tid] = Wf[tid];
    __syncthreads();

    const int h = tid & 15;
    const int b = blockIdx.x * 8 + (tid >> 4);
    const float4* hp = (const float4*)(h2ws + (size_t)b * 128);
    float acc = 0.f;
#pragma unroll
    for (int k4 = 0; k4 < 32; ++k4) {
        const float4 hv = hp[k4];
        acc = fmaf(hv.x, w3s[(k4 * 4 + 0) * 16 + h], acc);
        acc = fmaf(hv.y, w3s[(k4 * 4 + 1) * 16 + h], acc);
        acc = fmaf(hv.z, w3s[(k4 * 4 + 2) * 16 + h], acc);
        acc = fmaf(hv.w, w3s[(k4 * 4 + 3) * 16 + h], acc);
    }
    float v = sigf(acc) * wfs[h];
    v += __shfl_down(v, 8, 16);
    v += __shfl_down(v, 4, 16);
    v += __shfl_down(v, 2, 16);
    v += __shfl_down(v, 1, 16);
    if (h == 0) out[b] = v;
}

extern "C" void kernel_launch(void* const* d_in, const int* in_sizes, int n_in,
                              void* d_out, int out_size, void* d_ws, size_t ws_size,
                              hipStream_t stream) {
    const float* x  = (const float*)d_in[0];
    const float* Wg = (const float*)d_in[1];
    const float* bg = (const float*)d_in[2];
    const float* W0 = (const float*)d_in[3];
    const float* W1 = (const float*)d_in[4];
    const float* W2 = (const float*)d_in[5];
    const float* W3 = (const float*)d_in[6];
    const float* Wf = (const float*)d_in[7];
    float* out = (float*)d_out;

    char* ws = (char*)d_ws;
    float* h2            = (float*)ws;                               // 2 MB
    unsigned short* W1t  = (unsigned short*)(ws + (2u << 20));       // 256 KB
    unsigned short* W2t  = (unsigned short*)(ws + (2u << 20) + (256u << 10)); // 32 KB
    float* W0g           = (float*)(ws + (2u << 20) + (512u << 10)); // 256 KB
    float* bias0         = (float*)(ws + (2u << 20) + (768u << 10)); // 32 KB

    k_prep<<<dim3(104), dim3(256), 0, stream>>>(W1, W2, W0, Wg, bg, W1t, W2t, W0g, bias0);
    k_tree<<<dim3((4096 / TB) * 8), dim3(256), 0, stream>>>(x, W0g, bias0, W1t, W2t, h2);
    k_root<<<dim3(4096 / 8), dim3(128), 0, stream>>>(h2, W3, Wf, out);
}

// Round 9
// 129.438 us; speedup vs baseline: 1.2546x; 1.2546x over previous
//
#include <hip/hip_runtime.h>
#include <hip/hip_bf16.h>

// RestrictedNN DAG. Round 9: persistent blocks + pipelined x DMA.
//  - 2048 blocks; each owns subtree s (=blockIdx&7) and FOUR TB=4 batch tiles.
//  - Weights (folded W0g=Wg*W0 in W0-identical [m][g][h] layout, bias0,
//    W1t fragments) loaded ONCE per block; amortized over 4 tiles.
//  - x tiles double-buffered in LDS via global_load_lds: DMA for tile g+1
//    issues before phase A of tile g (latency hides under compute).
// B=4096, L0=512 leaves (G=8,H=16), L1=64, L2=8 (FAN=8), root 128->16.

#define TB 4
#define NITER 4
#define H0S 1032     // ushorts per h0 row (1024+8): 516 dw == 4 mod 32
#define H1S 136      // ushorts per h1 row (128+8)

typedef __attribute__((ext_vector_type(8))) short short8;
typedef __attribute__((ext_vector_type(4))) float floatx4;
typedef __attribute__((address_space(3))) void lds_void;
typedef const __attribute__((address_space(1))) void gbl_void;

__device__ __forceinline__ float sigf(float v) {
    return __builtin_amdgcn_rcpf(1.0f + __expf(-v));
}
__device__ __forceinline__ unsigned int f2bf_u32(float f) {   // RNE, bf16 in low 16
    unsigned int u = __builtin_bit_cast(unsigned int, f);
    return (u + 0x7fffu + ((u >> 16) & 1u)) >> 16;
}
__device__ __forceinline__ unsigned short f2bf(float f) {
    return (unsigned short)f2bf_u32(f);
}
__device__ __forceinline__ unsigned int f2bf2(float lo, float hi) {
    return f2bf_u32(lo) | (f2bf_u32(hi) << 16);
}

// ---- prep: W1/W2 -> bf16 fragment layout; W0g = Wg(*)W0 (same layout as W0),
// bias0[m][h] = sum_g bg[m][g]*W0[m][g][h] ----
__global__ __launch_bounds__(256) void k_prep(
    const float* __restrict__ W1, const float* __restrict__ W2,
    const float* __restrict__ W0, const float* __restrict__ Wg,
    const float* __restrict__ bg,
    unsigned short* __restrict__ W1t, unsigned short* __restrict__ W2t,
    float* __restrict__ W0g, float* __restrict__ bias0)
{
    __shared__ float wl[128 * 17];
    const int mb = blockIdx.x;
    const int tid = threadIdx.x;
    if (mb < 72) {                          // 0..63 -> W1t, 64..71 -> W2t
        const float* src = (mb < 64) ? (W1 + (size_t)mb * 2048)
                                     : (W2 + (size_t)(mb - 64) * 2048);
        unsigned short* dst = (mb < 64) ? (W1t + (size_t)mb * 2048)
                                        : (W2t + (size_t)(mb - 64) * 2048);
#pragma unroll
        for (int i = 0; i < 8; ++i) {
            const int idx = tid + i * 256;  // [k][h] in, coalesced
            wl[(idx >> 4) * 17 + (idx & 15)] = src[idx];
        }
        __syncthreads();
#pragma unroll
        for (int i = 0; i < 4; ++i) {
            const int u = tid + i * 256;    // uint index over [h][k] bf16 out
            const int h = u >> 6;
            const int k = (u & 63) * 2;
            ((unsigned int*)dst)[u] = f2bf2(wl[k * 17 + h], wl[(k + 1) * 17 + h]);
        }
    } else {                                // 72..103: W0g (elementwise) + bias0
        const size_t base = (size_t)(mb - 72) * 2048;   // 16 modules * 128
#pragma unroll
        for (int i = 0; i < 8; ++i) {
            const int idx = tid + i * 256;              // coalesced over [m][g][h]
            const int gm = (mb - 72) * 16 + (idx >> 7);
            const int g  = (idx >> 4) & 7;
            W0g[base + idx] = W0[base + idx] * Wg[gm * 8 + g];
        }
        const int gm = (mb - 72) * 16 + (tid >> 4);
        const int h  = tid & 15;
        float bias = 0.f;
#pragma unroll
        for (int g = 0; g < 8; ++g)
            bias = fmaf(bg[gm * 8 + g], W0[(size_t)gm * 128 + g * 16 + h], bias);
        bias0[gm * 16 + h] = bias;
    }
}

__global__ __launch_bounds__(256) void k_tree(
    const float* __restrict__ x, const float* __restrict__ W0g,
    const float* __restrict__ bias0,
    const unsigned short* __restrict__ W1t, const unsigned short* __restrict__ W2t,
    float* __restrict__ h2ws)
{
    __shared__ __align__(16) float xs[2][TB * 512];          // 2 x 8192 B (DMA, no pad)
    __shared__ __align__(16) unsigned short h0s[TB * H0S];   // 8256 B
    __shared__ __align__(16) unsigned short h1s[TB * H1S];   // 1088 B (25.7 KB total)

    const int tid   = threadIdx.x;
    const int s     = blockIdx.x & 7;         // subtree == h2 module (== XCD slice)
    const int chunk = blockIdx.x >> 3;        // 0..255: rows chunk*16 .. +15
    const int lane  = tid & 63;
    const int wv    = tid >> 6;
    const int m_l   = tid >> 2;               // local leaf module 0..63
    const int hq    = tid & 3;                // h quad
    const int m     = s * 64 + m_l;
    const int n     = lane & 15, q = lane >> 4;

    // ---------- DMA issue helper: tile g -> xs[buf] ----------
    auto dma_tile = [&](int g, int buf) {
        const float* xbase = x + (size_t)(chunk * 16 + g * 4) * 4096 + s * 512;
#pragma unroll
        for (int t = 0; t < 2; ++t) {
            const int i    = (t * 4 + wv) * 64 + lane;   // float4 units over 4x128
            const int row  = i >> 7;
            const int colf = (i & 127) * 4;
            gbl_void* gp = (gbl_void*)(xbase + (size_t)row * 4096 + colf);
            lds_void* lp = (lds_void*)((char*)xs[buf] + (size_t)(t * 4 + wv) * 1024);
            __builtin_amdgcn_global_load_lds(gp, lp, 16, 0, 0);
        }
    };

    // ---------- issue first tile, then load all weights under its shadow ----
    dma_tile(0, 0);

    float4 wA[8];                             // W0g[m][g][hq*4..+3], lane-contiguous
#pragma unroll
    for (int g = 0; g < 8; ++g)
        wA[g] = *(const float4*)(W0g + (size_t)m * 128 + g * 16 + hq * 4);
    const float4 bv = *(const float4*)(bias0 + m * 16 + hq * 4);
    const float bb[4] = {bv.x, bv.y, bv.z, bv.w};

    short8 w1r[2][4];                         // both phase-B modules for this wave
#pragma unroll
    for (int jj = 0; jj < 2; ++jj) {
        const unsigned short* w1m =
            W1t + ((size_t)(s * 8 + wv * 2 + jj) * 16 + n) * 128 + q * 8;
#pragma unroll
        for (int ks = 0; ks < 4; ++ks) w1r[jj][ks] = *(const short8*)(w1m + ks * 32);
    }
    __syncthreads();   // drains DMA tile 0 + weight loads

    // ---------- persistent loop over 4 tiles ----------
#pragma unroll
    for (int g = 0; g < NITER; ++g) {
        if (g + 1 < NITER) dma_tile(g + 1, (g + 1) & 1);   // prefetch next tile

        // phase A: h0 = sigmoid(x @ W0g + bias0)
        {
            const float* xb = &xs[g & 1][m_l * 8];
            unsigned short* h0base = &h0s[m_l * 16 + hq * 4];
#pragma unroll
            for (int b = 0; b < TB; ++b) {
                const float4 x0 = *(const float4*)(xb + b * 512);
                const float4 x1 = *(const float4*)(xb + b * 512 + 4);
                float a[4];
#pragma unroll
                for (int hi = 0; hi < 4; ++hi) {
                    float v = bb[hi];
                    v = fmaf(x0.x, wA[0][hi], v);
                    v = fmaf(x0.y, wA[1][hi], v);
                    v = fmaf(x0.z, wA[2][hi], v);
                    v = fmaf(x0.w, wA[3][hi], v);
                    v = fmaf(x1.x, wA[4][hi], v);
                    v = fmaf(x1.y, wA[5][hi], v);
                    v = fmaf(x1.z, wA[6][hi], v);
                    v = fmaf(x1.w, wA[7][hi], v);
                    a[hi] = v;
                }
                *(uint2*)(h0base + b * H0S) =
                    make_uint2(f2bf2(sigf(a[0]), sigf(a[1])),
                               f2bf2(sigf(a[2]), sigf(a[3])));
            }
        }
        __syncthreads();

        // phase B: h1 MFMA, wave wv -> modules {2wv, 2wv+1}
        // TB=4 < M=16: A rows duplicate (n&3); only q==0 C rows written.
        {
            const int j0 = wv * 2;
            const unsigned short* am0 = &h0s[(n & 3) * H0S + j0 * 128 + q * 8];
            floatx4 acc0 = {0.f, 0.f, 0.f, 0.f};
#pragma unroll
            for (int ks = 0; ks < 4; ++ks) {
                const short8 av = *(const short8*)(am0 + ks * 32);
                acc0 = __builtin_amdgcn_mfma_f32_16x16x32_bf16(av, w1r[0][ks], acc0, 0, 0, 0);
            }
            if (q == 0) {
#pragma unroll
                for (int r = 0; r < 4; ++r)
                    h1s[r * H1S + j0 * 16 + n] = f2bf(sigf(acc0[r]));
            }
            const unsigned short* am1 = am0 + 128;
            floatx4 acc1 = {0.f, 0.f, 0.f, 0.f};
#pragma unroll
            for (int ks = 0; ks < 4; ++ks) {
                const short8 av = *(const short8*)(am1 + ks * 32);
                acc1 = __builtin_amdgcn_mfma_f32_16x16x32_bf16(av, w1r[1][ks], acc1, 0, 0, 0);
            }
            if (q == 0) {
#pragma unroll
                for (int r = 0; r < 4; ++r)
                    h1s[r * H1S + (j0 + 1) * 16 + n] = f2bf(sigf(acc1[r]));
            }
        }
        __syncthreads();

        // phase C: h2 MFMA (module s), wave 0; W2t fragments lazy per tile
        if (wv == 0) {
            short8 w2r[4];
            const unsigned short* w2m = W2t + ((size_t)s * 16 + n) * 128 + q * 8;
#pragma unroll
            for (int ks = 0; ks < 4; ++ks) w2r[ks] = *(const short8*)(w2m + ks * 32);
            const unsigned short* am = &h1s[(n & 3) * H1S + q * 8];
            floatx4 acc = {0.f, 0.f, 0.f, 0.f};
#pragma unroll
            for (int ks = 0; ks < 4; ++ks) {
                const short8 av = *(const short8*)(am + ks * 32);
                acc = __builtin_amdgcn_mfma_f32_16x16x32_bf16(av, w2r[ks], acc, 0, 0, 0);
            }
            if (q == 0) {
                const int b0 = chunk * 16 + g * 4;
#pragma unroll
                for (int r = 0; r < 4; ++r)
                    h2ws[(size_t)(b0 + r) * 128 + s * 16 + n] = sigf(acc[r]);
            }
        }
        __syncthreads();   // h0s/h1s + xs buffer reuse safety
    }
}

// ---------- kernel: root (128->16, sigmoid) + final dot(16) ----------
__global__ __launch_bounds__(128) void k_root(
    const float* __restrict__ h2ws, const float* __restrict__ W3,
    const float* __restrict__ Wf, float* __restrict__ out)
{
    __shared__ float w3s[2048];
    __shared__ float wfs[16];
    const int tid = threadIdx.x;
#pragma unroll
    for (int t = 0; t < 16; ++t) w3s[tid + t * 128] = W3[tid + t * 128];
    if (tid < 16) wfs[tid] = Wf[tid];
    __syncthreads();

    const int h = tid & 15;
    const int b = blockIdx.x * 8 + (tid >> 4);
    const float4* hp = (const float4*)(h2ws + (size_t)b * 128);
    float acc = 0.f;
#pragma unroll
    for (int k4 = 0; k4 < 32; ++k4) {
        const float4 hv = hp[k4];
        acc = fmaf(hv.x, w3s[(k4 * 4 + 0) * 16 + h], acc);
        acc = fmaf(hv.y, w3s[(k4 * 4 + 1) * 16 + h], acc);
        acc = fmaf(hv.z, w3s[(k4 * 4 + 2) * 16 + h], acc);
        acc = fmaf(hv.w, w3s[(k4 * 4 + 3) * 16 + h], acc);
    }
    float v = sigf(acc) * wfs[h];
    v += __shfl_down(v, 8, 16);
    v += __shfl_down(v, 4, 16);
    v += __shfl_down(v, 2, 16);
    v += __shfl_down(v, 1, 16);
    if (h == 0) out[b] = v;
}

extern "C" void kernel_launch(void* const* d_in, const int* in_sizes, int n_in,
                              void* d_out, int out_size, void* d_ws, size_t ws_size,
                              hipStream_t stream) {
    const float* x  = (const float*)d_in[0];
    const float* Wg = (const float*)d_in[1];
    const float* bg = (const float*)d_in[2];
    const float* W0 = (const float*)d_in[3];
    const float* W1 = (const float*)d_in[4];
    const float* W2 = (const float*)d_in[5];
    const float* W3 = (const float*)d_in[6];
    const float* Wf = (const float*)d_in[7];
    float* out = (float*)d_out;

    char* ws = (char*)d_ws;
    float* h2            = (float*)ws;                               // 2 MB
    unsigned short* W1t  = (unsigned short*)(ws + (2u << 20));       // 256 KB
    unsigned short* W2t  = (unsigned short*)(ws + (2u << 20) + (256u << 10)); // 32 KB
    float* W0g           = (float*)(ws + (2u << 20) + (512u << 10)); // 256 KB
    float* bias0         = (float*)(ws + (2u << 20) + (768u << 10)); // 32 KB

    k_prep<<<dim3(104), dim3(256), 0, stream>>>(W1, W2, W0, Wg, bg, W1t, W2t, W0g, bias0);
    k_tree<<<dim3(2048), dim3(256), 0, stream>>>(x, W0g, bias0, W1t, W2t, h2);
    k_root<<<dim3(4096 / 8), dim3(128), 0, stream>>>(h2, W3, Wf, out);
}

// Round 10
// 123.840 us; speedup vs baseline: 1.3113x; 1.0452x over previous
//
#include <hip/hip_runtime.h>
#include <hip/hip_bf16.h>

// RestrictedNN DAG. Round 10: h0 GEMM moved to MFMA via block-diagonal
// zero-padded weight fragments (W0z), sigmoid via exp2 with -log2e folded
// into weights+bias. Phase A reads x directly from global (line-dense).
// B=4096, L0=512 leaves (G=8,H=16), L1=64, L2=8 (FAN=8), root 128->16.
//
// k_prep: W1t/W2t bf16 fragment transpose (as before);
//         W0z[m] = 32x16 bf16 B-fragment, rows q==m&3 hold -log2e*Wg*W0, else 0;
//         cbias[m][h] = -log2e * sum_g bg*W0.
// k_tree: 2048 blocks x 256. 16 rows x subtree s. A: 16 MFMA/wave -> h0;
//         B: h1 MFMA; C: h2 MFMA. LDS = h0s+h1s only (37 KB).

#define H0S 1032     // ushorts per h0 row (1024+8): 516 dw == 4 mod 32
#define H1S 136      // ushorts per h1 row (128+8)
#define C2N (-1.4426950408889634f)   // -log2(e)

typedef __attribute__((ext_vector_type(8))) short short8;
typedef __attribute__((ext_vector_type(4))) float floatx4;
typedef __attribute__((ext_vector_type(4))) unsigned int uint4v;

__device__ __forceinline__ float sigf(float v) {
    return __builtin_amdgcn_rcpf(1.0f + __expf(-v));
}
__device__ __forceinline__ unsigned int f2bf_u32(float f) {   // RNE, bf16 in low 16
    unsigned int u = __builtin_bit_cast(unsigned int, f);
    return (u + 0x7fffu + ((u >> 16) & 1u)) >> 16;
}
__device__ __forceinline__ unsigned short f2bf(float f) {
    return (unsigned short)f2bf_u32(f);
}
__device__ __forceinline__ unsigned int f2bf2(float lo, float hi) {
    return f2bf_u32(lo) | (f2bf_u32(hi) << 16);
}

// ---- prep: W1t/W2t fragment transpose; W0z block-diag fragments; cbias ----
__global__ __launch_bounds__(256) void k_prep(
    const float* __restrict__ W1, const float* __restrict__ W2,
    const float* __restrict__ W0, const float* __restrict__ Wg,
    const float* __restrict__ bg,
    unsigned short* __restrict__ W1t, unsigned short* __restrict__ W2t,
    unsigned int* __restrict__ W0z, float* __restrict__ cbias)
{
    __shared__ float wl[128 * 17];
    const int mb = blockIdx.x;
    const int tid = threadIdx.x;
    if (mb < 72) {                          // 0..63 -> W1t, 64..71 -> W2t
        const float* src = (mb < 64) ? (W1 + (size_t)mb * 2048)
                                     : (W2 + (size_t)(mb - 64) * 2048);
        unsigned short* dst = (mb < 64) ? (W1t + (size_t)mb * 2048)
                                        : (W2t + (size_t)(mb - 64) * 2048);
#pragma unroll
        for (int i = 0; i < 8; ++i) {
            const int idx = tid + i * 256;  // [k][h] in, coalesced
            wl[(idx >> 4) * 17 + (idx & 15)] = src[idx];
        }
        __syncthreads();
#pragma unroll
        for (int i = 0; i < 4; ++i) {
            const int u = tid + i * 256;    // uint index over [h][k] bf16 out
            const int h = u >> 6;
            const int k = (u & 63) * 2;
            ((unsigned int*)dst)[u] = f2bf2(wl[k * 17 + h], wl[(k + 1) * 17 + h]);
        }
    } else {                                // 72..103: W0z + cbias, 16 modules/block
        const int mb2 = mb - 72;            // 0..31
        // W0z: per module 256 uints = fragment [lane l][j2]; B[k][n] with
        // k=q*8+j, n=l&15; nonzero only when q == (m&3).
#pragma unroll
        for (int t = 0; t < 16; ++t) {
            const int idx  = tid + t * 256;          // 0..4095
            const int mloc = idx >> 8;
            const int rem  = idx & 255;
            const int l    = rem >> 2;
            const int j2   = rem & 3;
            const int m    = mb2 * 16 + mloc;
            const int n    = l & 15;
            const int q    = l >> 4;
            unsigned int v = 0u;
            if (q == (m & 3)) {
                const int g0 = 2 * j2;
                const float f0 = C2N * Wg[m * 8 + g0]     * W0[(size_t)m * 128 + g0 * 16 + n];
                const float f1 = C2N * Wg[m * 8 + g0 + 1] * W0[(size_t)m * 128 + (g0 + 1) * 16 + n];
                v = f2bf2(f0, f1);
            }
            W0z[(size_t)m * 256 + rem] = v;
        }
        // cbias[m][n] = C2N * sum_g bg[m][g] * W0[m][g][n]
        const int m = mb2 * 16 + (tid >> 4);
        const int n = tid & 15;
        float acc = 0.f;
#pragma unroll
        for (int g = 0; g < 8; ++g)
            acc = fmaf(bg[m * 8 + g], W0[(size_t)m * 128 + g * 16 + n], acc);
        cbias[m * 16 + n] = C2N * acc;
    }
}

__global__ __launch_bounds__(256) void k_tree(
    const float* __restrict__ x, const unsigned int* __restrict__ W0z,
    const float* __restrict__ cbias,
    const unsigned short* __restrict__ W1t, const unsigned short* __restrict__ W2t,
    float* __restrict__ h2ws)
{
    __shared__ __align__(16) unsigned short h0s[16 * H0S];   // 33024 B
    __shared__ __align__(16) unsigned short h1s[16 * H1S];   //  4352 B (37.4 KB)

    const int tid  = threadIdx.x;
    const int s    = blockIdx.x & 7;          // subtree == h2 module
    const int b0   = (blockIdx.x >> 3) * 16;  // batch tile base
    const int lane = tid & 63;
    const int wv   = tid >> 6;
    const int n    = lane & 15;               // MFMA row/col lane index
    const int q    = lane >> 4;               // MFMA k-quad / C row group

    // ---------- phase A: h0 via MFMA, 4 groups x 4 modules per wave ----------
    // A-fragment lane(n,q): x[b0+n][s*512 + mg*32 + q*8 + j], j=0..7 (32B f32)
    {
        const float* xrow = x + (size_t)(b0 + n) * 4096 + s * 512 + q * 8;
#pragma unroll
        for (int gi = 0; gi < 4; ++gi) {
            const int mg = wv * 4 + gi;                 // local module group 0..15
            const float* xg = xrow + mg * 32;
            const float4 xa = *(const float4*)xg;
            const float4 xb = *(const float4*)(xg + 4);
            const uint4v up = {f2bf2(xa.x, xa.y), f2bf2(xa.z, xa.w),
                               f2bf2(xb.x, xb.y), f2bf2(xb.z, xb.w)};
            const short8 af = __builtin_bit_cast(short8, up);
#pragma unroll
            for (int pi = 0; pi < 4; ++pi) {
                const int m_l = mg * 4 + pi;            // local leaf module 0..63
                const int m   = s * 64 + m_l;
                const short8 bz = *(const short8*)(W0z + (size_t)m * 256 + lane * 4);
                const float cb = cbias[m * 16 + n];
                floatx4 acc = {0.f, 0.f, 0.f, 0.f};
                acc = __builtin_amdgcn_mfma_f32_16x16x32_bf16(af, bz, acc, 0, 0, 0);
                // C rows = q*4+r (batch), col = n (h). sigma = 1/(1+2^(C+cb)).
#pragma unroll
                for (int r = 0; r < 4; ++r) {
                    const float e = __builtin_amdgcn_exp2f(acc[r] + cb);
                    h0s[(q * 4 + r) * H0S + m_l * 16 + n] =
                        f2bf(__builtin_amdgcn_rcpf(1.0f + e));
                }
            }
        }
    }
    __syncthreads();

    // ---------- phase B: h1 MFMA, wave wv -> modules {2wv, 2wv+1} ----------
    {
#pragma unroll
        for (int jj = 0; jj < 2; ++jj) {
            const int j = wv * 2 + jj;
            const unsigned short* w1m =
                W1t + ((size_t)(s * 8 + j) * 16 + n) * 128 + q * 8;
            const unsigned short* am = &h0s[n * H0S + j * 128 + q * 8];
            floatx4 acc = {0.f, 0.f, 0.f, 0.f};
#pragma unroll
            for (int ks = 0; ks < 4; ++ks) {
                const short8 av = *(const short8*)(am + ks * 32);
                const short8 bv = *(const short8*)(w1m + ks * 32);
                acc = __builtin_amdgcn_mfma_f32_16x16x32_bf16(av, bv, acc, 0, 0, 0);
            }
#pragma unroll
            for (int r = 0; r < 4; ++r)
                h1s[(q * 4 + r) * H1S + j * 16 + n] = f2bf(sigf(acc[r]));
        }
    }
    __syncthreads();

    // ---------- phase C: h2 MFMA (module s), wave 0 only ----------
    if (wv == 0) {
        const unsigned short* w2m = W2t + ((size_t)s * 16 + n) * 128 + q * 8;
        const unsigned short* am = &h1s[n * H1S + q * 8];
        floatx4 acc = {0.f, 0.f, 0.f, 0.f};
#pragma unroll
        for (int ks = 0; ks < 4; ++ks) {
            const short8 av = *(const short8*)(am + ks * 32);
            const short8 bv = *(const short8*)(w2m + ks * 32);
            acc = __builtin_amdgcn_mfma_f32_16x16x32_bf16(av, bv, acc, 0, 0, 0);
        }
#pragma unroll
        for (int r = 0; r < 4; ++r)
            h2ws[(size_t)(b0 + q * 4 + r) * 128 + s * 16 + n] = sigf(acc[r]);
    }
}

// ---------- kernel: root (128->16, sigmoid) + final dot(16) ----------
__global__ __launch_bounds__(128) void k_root(
    const float* __restrict__ h2ws, const float* __restrict__ W3,
    const float* __restrict__ Wf, float* __restrict__ out)
{
    __shared__ float w3s[2048];
    __shared__ float wfs[16];
    const int tid = threadIdx.x;
#pragma unroll
    for (int t = 0; t < 16; ++t) w3s[tid + t * 128] = W3[tid + t * 128];
    if (tid < 16) wfs[tid] = Wf[tid];
    __syncthreads();

    const int h = tid & 15;
    const int b = blockIdx.x * 8 + (tid >> 4);
    const float4* hp = (const float4*)(h2ws + (size_t)b * 128);
    float acc = 0.f;
#pragma unroll
    for (int k4 = 0; k4 < 32; ++k4) {
        const float4 hv = hp[k4];
        acc = fmaf(hv.x, w3s[(k4 * 4 + 0) * 16 + h], acc);
        acc = fmaf(hv.y, w3s[(k4 * 4 + 1) * 16 + h], acc);
        acc = fmaf(hv.z, w3s[(k4 * 4 + 2) * 16 + h], acc);
        acc = fmaf(hv.w, w3s[(k4 * 4 + 3) * 16 + h], acc);
    }
    float v = sigf(acc) * wfs[h];
    v += __shfl_down(v, 8, 16);
    v += __shfl_down(v, 4, 16);
    v += __shfl_down(v, 2, 16);
    v += __shfl_down(v, 1, 16);
    if (h == 0) out[b] = v;
}

extern "C" void kernel_launch(void* const* d_in, const int* in_sizes, int n_in,
                              void* d_out, int out_size, void* d_ws, size_t ws_size,
                              hipStream_t stream) {
    const float* x  = (const float*)d_in[0];
    const float* Wg = (const float*)d_in[1];
    const float* bg = (const float*)d_in[2];
    const float* W0 = (const float*)d_in[3];
    const float* W1 = (const float*)d_in[4];
    const float* W2 = (const float*)d_in[5];
    const float* W3 = (const float*)d_in[6];
    const float* Wf = (const float*)d_in[7];
    float* out = (float*)d_out;

    char* ws = (char*)d_ws;
    float* h2            = (float*)ws;                               // 2 MB
    unsigned short* W1t  = (unsigned short*)(ws + (2u << 20));       // 256 KB
    unsigned short* W2t  = (unsigned short*)(ws + (2u << 20) + (256u << 10)); // 32 KB
    unsigned int*   W0z  = (unsigned int*)(ws + (3u << 20));         // 512 KB
    float*          cbias = (float*)(ws + (3u << 20) + (512u << 10)); // 32 KB

    k_prep<<<dim3(104), dim3(256), 0, stream>>>(W1, W2, W0, Wg, bg,
                                                W1t, W2t, W0z, cbias);
    k_tree<<<dim3(2048), dim3(256), 0, stream>>>(x, W0z, cbias, W1t, W2t, h2);
    k_root<<<dim3(4096 / 8), dim3(128), 0, stream>>>(h2, W3, Wf, out);
}